// Round 5
// baseline (49.964 us; speedup 1.0000x reference)
//
#include <hip/hip_runtime.h>
#include <stdint.h>

#define NUM_BBOX    2
#define NUM_CLASSES 20
#define NUM_GRID    7
#define BATCH       64
#define NCELL  (BATCH * NUM_GRID * NUM_GRID)   // 3136
#define NCAND  (NCELL * NUM_BBOX)              // 6272
#define CPB    49                              // cells per batch
#define KPB    98                              // candidates per batch

// ---- workspace layout (bytes) ----
#define WS_SCORE     0         // f32[6272]            25088
#define WS_CELLBOX   25088     // f32[3136*4]          50176
#define WS_CELLLAB   75264     // f32[3136]            12544
#define WS_KEYS      87808     // u64[6272]            50176
#define WS_KEEP      137984    // f32[6272]            25088

// monotone float -> sortable u32 (ascending float == ascending u32)
__device__ __forceinline__ unsigned fkey(float f) {
    unsigned u = __float_as_uint(f);
    return (u & 0x80000000u) ? ~u : (u | 0x80000000u);
}

__device__ __forceinline__ float iou_rn(float4 a, float4 b) {
    float xx1 = fmaxf(a.x, b.x), yy1 = fmaxf(a.y, b.y);
    float xx2 = fminf(a.z, b.z), yy2 = fminf(a.w, b.w);
    float w = fmaxf(__fsub_rn(xx2, xx1), 0.0f);
    float h = fmaxf(__fsub_rn(yy2, yy1), 0.0f);
    float inter = __fmul_rn(w, h);
    float aa = __fmul_rn(__fsub_rn(a.z, a.x), __fsub_rn(a.w, a.y));
    float ab = __fmul_rn(__fsub_rn(b.z, b.x), __fsub_rn(b.w, b.y));
    float denom = __fadd_rn(__fsub_rn(__fadd_rn(aa, ab), inter), 1e-9f);
    return __fdiv_rn(inter, denom);
}

// One block per batch: decode the batch's 49 cells, then run its 20
// (batch,label) NMS groups in-block (wave 0: labels 1..10, wave 1: 11..20).
__global__ void __launch_bounds__(128) k_decode_nms(
        const float* __restrict__ in,
        float* __restrict__ score,
        float* __restrict__ cellBox,
        float* __restrict__ cellLabel,
        unsigned long long* __restrict__ keys,
        float* __restrict__ keepOrig) {
    __shared__ float2 raw2[1225];                 // 49*50 floats
    __shared__ unsigned long long lkey[KPB];
    __shared__ float4 lbox[CPB];
    __shared__ int    llab[CPB];
    __shared__ float  lkeep[KPB];
    __shared__ unsigned long long mkey[2][KPB];
    __shared__ unsigned long long skey[2][KPB];

    const int b    = blockIdx.x;
    const int tid  = (int)threadIdx.x;
    const int lane = tid & 63;
    const int wv   = tid >> 6;
    const int base = b * KPB;

    const float2* src = (const float2*)(in + b * (CPB * 50));
    for (int i = tid; i < 1225; i += 128) raw2[i] = src[i];
    if (tid < KPB) lkeep[tid] = 0.0f;
    __syncthreads();

    if (tid < CPB) {
        const float* p = (const float*)raw2 + tid * 50;
        int r = tid / NUM_GRID, c = tid % NUM_GRID;

        float sc[NUM_BBOX];
        for (int bb = 0; bb < NUM_BBOX; ++bb) {
            const float* q = p + bb * 25;
            float conf = q[4];
            float m = __fmul_rn(q[5], conf);
            for (int k = 1; k < NUM_CLASSES; ++k)
                m = fmaxf(m, __fmul_rn(q[5 + k], conf));
            sc[bb] = m;
        }
        int best = (sc[1] > sc[0]) ? 1 : 0;       // first-occurrence argmax
        const float* q = p + best * 25;

        int lab = 0; float bv = q[5];
        for (int k = 1; k < NUM_CLASSES; ++k)
            if (q[5 + k] > bv) { bv = q[5 + k]; lab = k; }

        float x  = __fdiv_rn(__fadd_rn(q[0], (float)r), 7.0f);
        float y  = __fdiv_rn(__fadd_rn(q[1], (float)c), 7.0f);
        float hw = __fmul_rn(q[2], 0.5f);
        float hh = __fmul_rn(q[3], 0.5f);
        float4 bx = make_float4(__fsub_rn(x, hw), __fsub_rn(y, hh),
                                __fadd_rn(x, hw), __fadd_rn(y, hh));

        int cell = b * CPB + tid;
        *(float4*)(cellBox + cell * 4) = bx;
        cellLabel[cell] = (float)(lab + 1);
        lbox[tid] = bx;
        llab[tid] = lab + 1;

        for (int bb = 0; bb < NUM_BBOX; ++bb) {
            int idx = cell * 2 + bb;              // == base + 2*tid + bb
            score[idx] = sc[bb];
            bool valid = sc[bb] > 0.5f;
            float kf = valid ? -sc[bb] : __builtin_inff();
            unsigned long long key = ((unsigned long long)fkey(kf) << 32) | (unsigned)idx;
            keys[idx] = key;
            lkey[tid * 2 + bb] = key;
        }
    }
    __syncthreads();

    // candidate slots: c0 = lane (<98 always), c1 = lane+64 (lane<34)
    unsigned long long key0 = lkey[lane];
    bool val0 = (unsigned)(key0 >> 32) < 0x80000000u;
    int lab0 = llab[lane >> 1];
    unsigned long long key1 = 0; bool val1 = false; int lab1 = -1;
    if (lane + 64 < KPB) {
        key1 = lkey[lane + 64];
        val1 = (unsigned)(key1 >> 32) < 0x80000000u;
        lab1 = llab[(lane + 64) >> 1];
    }

    for (int l = 0; l < 10; ++l) {
        int L = wv * 10 + l + 1;
        bool v0 = val0 && (lab0 == L);
        bool v1 = val1 && (lab1 == L);
        unsigned long long b0 = __ballot(v0);
        unsigned long long b1 = __ballot(v1);
        int n0 = __popcll(b0);
        int n  = n0 + __popcll(b1);
        unsigned long long below = (1ull << lane) - 1ull;
        __syncthreads();                          // A: prev-iter reads done
        if (v0) mkey[wv][__popcll(b0 & below)] = key0;
        if (v1) mkey[wv][n0 + __popcll(b1 & below)] = key1;
        __syncthreads();                          // B: compaction visible
        for (int s = 0; s < 2; ++s) {
            int j = lane + s * 64;
            if (j < n) {
                unsigned long long kj = mkey[wv][j];
                int rr = 0;
                for (int i2 = 0; i2 < n; ++i2) rr += (mkey[wv][i2] < kj) ? 1 : 0;
                skey[wv][rr] = kj;                // rank-by-count == stable sorted order
            }
        }
        __syncthreads();                          // C: sorted keys visible
        if (n > 0) {
            float4 box0 = make_float4(0.f, 0.f, 0.f, 0.f), box1 = box0;
            int t0 = 0, t1 = 0, keep0 = 0, keep1 = 0;
            if (lane < n) {
                t0 = (int)(unsigned)skey[wv][lane] - base;
                box0 = lbox[t0 >> 1];
                keep0 = 1;
            }
            if (lane + 64 < n) {
                t1 = (int)(unsigned)skey[wv][lane + 64] - base;
                box1 = lbox[t1 >> 1];
                keep1 = 1;
            }
            for (int i = 0; i < n; ++i) {
                int srcl = i & 63;
                int ki = __shfl((i < 64) ? keep0 : keep1, srcl);
                if (ki) {
                    float4 s4 = (i < 64) ? box0 : box1;
                    float4 bi;
                    bi.x = __shfl(s4.x, srcl);
                    bi.y = __shfl(s4.y, srcl);
                    bi.z = __shfl(s4.z, srcl);
                    bi.w = __shfl(s4.w, srcl);
                    if (keep0 && lane > i)      { if (iou_rn(bi, box0) > 0.3f) keep0 = 0; }
                    if (keep1 && lane + 64 > i) { if (iou_rn(bi, box1) > 0.3f) keep1 = 0; }
                }
            }
            if (keep0) lkeep[t0] = 1.0f;
            if (keep1) lkeep[t1] = 1.0f;
        }
    }
    __syncthreads();
    if (tid < KPB) keepOrig[base + tid] = lkeep[tid];
}

// 98 blocks x 512 threads: wave w counts keys[j]<my over j-chunk w (784 keys),
// LDS-reduce the 8 partials, wave 0 scatters all outputs at position rank.
__global__ void __launch_bounds__(512) k_rank_scatter(
        const unsigned long long* __restrict__ keys,
        const float* __restrict__ score,
        const float* __restrict__ cellBox,
        const float* __restrict__ cellLabel,
        const float* __restrict__ keepOrig,
        float* __restrict__ out) {
    __shared__ unsigned part[8][64];
    int lane = (int)threadIdx.x & 63;
    int wv   = (int)threadIdx.x >> 6;
    int i = blockIdx.x * 64 + lane;
    unsigned long long my = keys[i];
    int j0 = wv * (NCAND / 8);
    unsigned r = 0;
    #pragma unroll 8
    for (int j = j0; j < j0 + NCAND / 8; ++j)
        r += (keys[j] < my) ? 1u : 0u;
    part[wv][lane] = r;
    __syncthreads();
    if ((int)threadIdx.x < 64) {
        unsigned rr = 0;
        #pragma unroll
        for (int w = 0; w < 8; ++w) rr += part[w][lane];
        int cell = i >> 1;
        out[rr] = (float)(i / 98);                // batch id
        float4 bx = *(const float4*)(cellBox + cell * 4);
        *(float4*)(out + NCAND + rr * 4) = bx;
        out[NCAND * 5 + rr] = cellLabel[cell];
        out[NCAND * 6 + rr] = score[i];
        out[NCAND * 7 + rr] = keepOrig[i];
    }
}

extern "C" void kernel_launch(void* const* d_in, const int* in_sizes, int n_in,
                              void* d_out, int out_size, void* d_ws, size_t ws_size,
                              hipStream_t stream) {
    const float* in = (const float*)d_in[0];
    char* ws = (char*)d_ws;
    float*              score     = (float*)(ws + WS_SCORE);
    float*              cellBox   = (float*)(ws + WS_CELLBOX);
    float*              cellLabel = (float*)(ws + WS_CELLLAB);
    unsigned long long* keys      = (unsigned long long*)(ws + WS_KEYS);
    float*              keepOrig  = (float*)(ws + WS_KEEP);
    float* out = (float*)d_out;

    k_decode_nms<<<BATCH, 128, 0, stream>>>(in, score, cellBox, cellLabel, keys, keepOrig);
    k_rank_scatter<<<NCAND / 64, 512, 0, stream>>>(keys, score, cellBox, cellLabel, keepOrig, out);
}

// Round 6
// 37.377 us; speedup vs baseline: 1.3368x; 1.3368x over previous
//
#include <hip/hip_runtime.h>
#include <stdint.h>

#define NUM_BBOX    2
#define NUM_CLASSES 20
#define NUM_GRID    7
#define BATCH       64
#define NCELL  (BATCH * NUM_GRID * NUM_GRID)   // 3136
#define NCAND  (NCELL * NUM_BBOX)              // 6272
#define NGROUP (BATCH * NUM_CLASSES)           // 1280
#define MAXG   98

// ---- workspace layout (bytes) ----
#define WS_SCORE     0         // f32[6272]            25088
#define WS_CELLBOX   25088     // f32[3136*4]          50176
#define WS_CELLLAB   75264     // f32[3136]            12544
#define WS_KEYS      87808     // u64[6272]            50176
#define WS_KEEP      137984    // f32[6272]            25088

// monotone float -> sortable u32 (ascending float == ascending u32)
__device__ __forceinline__ unsigned fkey(float f) {
    unsigned u = __float_as_uint(f);
    return (u & 0x80000000u) ? ~u : (u | 0x80000000u);
}

__global__ void k_decode(const float* __restrict__ in,
                         float* __restrict__ score,
                         float* __restrict__ cellBox,
                         float* __restrict__ cellLabel,
                         unsigned long long* __restrict__ keys,
                         float* __restrict__ keepOrig) {
    int cell = blockIdx.x * blockDim.x + threadIdx.x;
    if (cell >= NCELL) return;
    const float* p = in + cell * (NUM_BBOX * (5 + NUM_CLASSES));
    int rc = cell % (NUM_GRID * NUM_GRID);
    int r = rc / NUM_GRID, c = rc % NUM_GRID;

    // per-bbox score = max_cls (prob*conf)  -- mul then max, matching reference
    float sc[NUM_BBOX];
    for (int bb = 0; bb < NUM_BBOX; ++bb) {
        const float* q = p + bb * 25;
        float conf = q[4];
        float m = __fmul_rn(q[5], conf);
        for (int k = 1; k < NUM_CLASSES; ++k)
            m = fmaxf(m, __fmul_rn(q[5 + k], conf));
        sc[bb] = m;
    }
    int best = (sc[1] > sc[0]) ? 1 : 0;   // first-occurrence argmax over 2
    const float* q = p + best * 25;

    // label = argmax over classes (first occurrence) + 1
    int lab = 0; float bv = q[5];
    for (int k = 1; k < NUM_CLASSES; ++k)
        if (q[5 + k] > bv) { bv = q[5 + k]; lab = k; }

    // box: x uses row index, y uses col index (as in reference)
    float x  = __fdiv_rn(__fadd_rn(q[0], (float)r), 7.0f);
    float y  = __fdiv_rn(__fadd_rn(q[1], (float)c), 7.0f);
    float hw = __fmul_rn(q[2], 0.5f);
    float hh = __fmul_rn(q[3], 0.5f);
    float x1 = __fsub_rn(x, hw), y1 = __fsub_rn(y, hh);
    float x2 = __fadd_rn(x, hw), y2 = __fadd_rn(y, hh);

    cellBox[cell * 4 + 0] = x1;
    cellBox[cell * 4 + 1] = y1;
    cellBox[cell * 4 + 2] = x2;
    cellBox[cell * 4 + 3] = y2;
    cellLabel[cell] = (float)(lab + 1);

    for (int bb = 0; bb < NUM_BBOX; ++bb) {
        int idx = cell * NUM_BBOX + bb;
        score[idx] = sc[bb];
        keepOrig[idx] = 0.0f;
        bool valid = sc[bb] > 0.5f;
        float kf = valid ? -sc[bb] : __builtin_inff();
        keys[idx] = ((unsigned long long)fkey(kf) << 32) | (unsigned)idx;
    }
}

__device__ __forceinline__ float iou_rn(float4 a, float4 b) {
    float xx1 = fmaxf(a.x, b.x), yy1 = fmaxf(a.y, b.y);
    float xx2 = fminf(a.z, b.z), yy2 = fminf(a.w, b.w);
    float w = fmaxf(__fsub_rn(xx2, xx1), 0.0f);
    float h = fmaxf(__fsub_rn(yy2, yy1), 0.0f);
    float inter = __fmul_rn(w, h);
    float aa = __fmul_rn(__fsub_rn(a.z, a.x), __fsub_rn(a.w, a.y));
    float ab = __fmul_rn(__fsub_rn(b.z, b.x), __fsub_rn(b.w, b.y));
    float denom = __fadd_rn(__fsub_rn(__fadd_rn(aa, ab), inter), 1e-9f);
    return __fdiv_rn(inter, denom);
}

// one 64-lane workgroup per (batch,label) group. Membership via ballot,
// order via rank-by-count (keys unique, == global sorted order restricted
// to the group), greedy suppression with wave-parallel IoU.
__global__ void __launch_bounds__(64) k_nms(
        const unsigned long long* __restrict__ keys,
        const float* __restrict__ cellLabel,
        const float* __restrict__ cellBox,
        float* __restrict__ keepOrig) {
    __shared__ unsigned long long mkey[MAXG];
    __shared__ unsigned long long skey[MAXG];
    int g = blockIdx.x;
    int lane = (int)threadIdx.x;
    int b = g / NUM_CLASSES;
    float lab = (float)(g % NUM_CLASSES + 1);
    int base = b * MAXG;

    // slot 0: candidate t = lane (< 98 always); slot 1: t = lane+64 (lane<34)
    unsigned long long key0 = keys[base + lane];
    bool v0 = ((unsigned)(key0 >> 32) < 0x80000000u) &&
              (cellLabel[(base + lane) >> 1] == lab);
    unsigned long long key1 = 0; bool v1 = false;
    if (lane + 64 < MAXG) {
        key1 = keys[base + lane + 64];
        v1 = ((unsigned)(key1 >> 32) < 0x80000000u) &&
             (cellLabel[(base + lane + 64) >> 1] == lab);
    }

    unsigned long long b0 = __ballot(v0);
    unsigned long long b1 = __ballot(v1);
    int n0 = __popcll(b0);
    int n  = n0 + __popcll(b1);
    if (n == 0) return;

    unsigned long long below = (1ull << lane) - 1ull;
    if (v0) mkey[__popcll(b0 & below)] = key0;
    if (v1) mkey[n0 + __popcll(b1 & below)] = key1;
    __syncthreads();

    // sorted position = # members with smaller key
    for (int s = 0; s < 2; ++s) {
        int j = lane + s * 64;
        if (j < n) {
            unsigned long long kj = mkey[j];
            int r = 0;
            for (int i = 0; i < n; ++i) r += (mkey[i] < kj) ? 1 : 0;
            skey[r] = kj;
        }
    }
    __syncthreads();

    // member j (sorted) lives on lane j&63, slot j>>6
    float4 box0 = make_float4(0.f, 0.f, 0.f, 0.f), box1 = box0;
    int idx0 = 0, idx1 = 0, keep0 = 0, keep1 = 0;
    if (lane < n) {
        idx0 = (int)(unsigned)skey[lane];
        box0 = *(const float4*)(cellBox + (idx0 >> 1) * 4);
        keep0 = 1;
    }
    if (lane + 64 < n) {
        idx1 = (int)(unsigned)skey[lane + 64];
        box1 = *(const float4*)(cellBox + (idx1 >> 1) * 4);
        keep1 = 1;
    }

    for (int i = 0; i < n; ++i) {
        int srcl = i & 63;
        int ki = __shfl((i < 64) ? keep0 : keep1, srcl);
        if (ki) {
            float4 src = (i < 64) ? box0 : box1;
            float4 bi;
            bi.x = __shfl(src.x, srcl);
            bi.y = __shfl(src.y, srcl);
            bi.z = __shfl(src.z, srcl);
            bi.w = __shfl(src.w, srcl);
            if (keep0 && lane > i) {
                if (iou_rn(bi, box0) > 0.3f) keep0 = 0;
            }
            if (keep1 && lane + 64 > i) {
                if (iou_rn(bi, box1) > 0.3f) keep1 = 0;
            }
        }
    }
    if (keep0) keepOrig[idx0] = 1.0f;
    if (keep1) keepOrig[idx1] = 1.0f;
}

// 98 blocks x 512 threads: wave w counts keys[j]<my over j-chunk w (784 keys),
// LDS-reduce the 8 partials, wave 0 scatters all outputs at position rank.
__global__ void __launch_bounds__(512) k_rank_scatter(
        const unsigned long long* __restrict__ keys,
        const float* __restrict__ score,
        const float* __restrict__ cellBox,
        const float* __restrict__ cellLabel,
        const float* __restrict__ keepOrig,
        float* __restrict__ out) {
    __shared__ unsigned part[8][64];
    int lane = (int)threadIdx.x & 63;
    int wv   = (int)threadIdx.x >> 6;
    int i = blockIdx.x * 64 + lane;
    unsigned long long my = keys[i];
    int j0 = wv * (NCAND / 8);
    unsigned r = 0;
    #pragma unroll 8
    for (int j = j0; j < j0 + NCAND / 8; ++j)
        r += (keys[j] < my) ? 1u : 0u;
    part[wv][lane] = r;
    __syncthreads();
    if ((int)threadIdx.x < 64) {
        unsigned rr = 0;
        #pragma unroll
        for (int w = 0; w < 8; ++w) rr += part[w][lane];
        int cell = i >> 1;
        out[rr] = (float)(i / 98);                // batch id
        float4 bx = *(const float4*)(cellBox + cell * 4);
        *(float4*)(out + NCAND + rr * 4) = bx;
        out[NCAND * 5 + rr] = cellLabel[cell];
        out[NCAND * 6 + rr] = score[i];
        out[NCAND * 7 + rr] = keepOrig[i];
    }
}

extern "C" void kernel_launch(void* const* d_in, const int* in_sizes, int n_in,
                              void* d_out, int out_size, void* d_ws, size_t ws_size,
                              hipStream_t stream) {
    const float* in = (const float*)d_in[0];
    char* ws = (char*)d_ws;
    float*              score     = (float*)(ws + WS_SCORE);
    float*              cellBox   = (float*)(ws + WS_CELLBOX);
    float*              cellLabel = (float*)(ws + WS_CELLLAB);
    unsigned long long* keys      = (unsigned long long*)(ws + WS_KEYS);
    float*              keepOrig  = (float*)(ws + WS_KEEP);
    float* out = (float*)d_out;

    k_decode<<<(NCELL + 63) / 64, 64, 0, stream>>>(in, score, cellBox, cellLabel,
                                                   keys, keepOrig);
    k_nms<<<NGROUP, 64, 0, stream>>>(keys, cellLabel, cellBox, keepOrig);
    k_rank_scatter<<<NCAND / 64, 512, 0, stream>>>(keys, score, cellBox, cellLabel,
                                                   keepOrig, out);
}